// Round 1
// baseline (145.088 us; speedup 1.0000x reference)
//
#include <hip/hip_runtime.h>

// DAG of 1x1 convs, fully fused, f16 MFMA, zero per-conv barriers.
// R7: wconv_kernel eliminated — W f32->f16 conversion folded into the
// (MFMA-hidden) per-conv W prefetch. One kernel, one less graph node.
// Each wave owns 32 pixels x all 64 channels; all state reuse is wave-private.
// Schedule (conv index k -> weight widx / src buf / acc / retire):
//  k  : 0  1  2  3  4  5  6  7  8  9 10 11 12 13 14 15
//  w  : 0  1  2  3  4  5  6  7 11  8 12  9 13 14 10 15   (0,1=pre; 2+e=edge e)
//  src: 2  3  0  1  0  1  2  0  0  1  1  2  2  3  3  0
//  acc: A  A  A  A  A  A  A  A  B  A  B  A  B  B  A  B
//  ret: s0 s1 -  n2 -  -  n3 -  -  -  -  -  -  -  n4 n5
// buffers: s0->0, s1->1, s2->2 (was xin0), s3->3 (was xin1), s4->0 (s0 dead)

typedef _Float16 f16;
typedef _Float16 f16x8 __attribute__((ext_vector_type(8)));
typedef float    f32x4 __attribute__((ext_vector_type(4)));

#define RSH 72            // f16 per state row (144B: 16B-aligned, 2-way banks)
#define SB  (64 * RSH)    // 4608 f16 = 9216 B per state buffer

__device__ __forceinline__ unsigned int pkrtz(float a, float b) {
    __fp16 h2 __attribute__((ext_vector_type(2))) = __builtin_amdgcn_cvt_pkrtz(a, b);
    return __builtin_bit_cast(unsigned int, h2);
}

// load 8 consecutive f32 and pack to f16x8 (same pkrtz as the old wconv kernel)
__device__ __forceinline__ f16x8 cvt8(const float* __restrict__ p) {
    float4 v0 = ((const float4*)p)[0];
    float4 v1 = ((const float4*)p)[1];
    union { uint4 u; f16x8 h; } r;
    r.u = make_uint4(pkrtz(v0.x, v0.y), pkrtz(v0.z, v0.w),
                     pkrtz(v1.x, v1.y), pkrtz(v1.z, v1.w));
    return r.h;
}

__global__ __launch_bounds__(128, 2) void dag_kernel(
    const float* __restrict__ x0, const float* __restrict__ x1,
    const float* __restrict__ Wpre, const float* __restrict__ Wedge,
    float* __restrict__ out)
{
    __shared__ __align__(16) f16 lds[4 * SB];   // 36864 B -> 4 blocks/CU

    const int t    = threadIdx.x;   // 128 threads = 2 waves
    const int lane = t & 63;
    const int wv   = t >> 6;        // wave owns pixels wv*32 .. wv*32+31
    const int pl   = lane & 15;
    const int q    = lane >> 4;

    const int blk = blockIdx.x;     // 1024 = 64 batches x 16 px-tiles (4/CU, no tail)
    const int b   = blk >> 4;
    const int hw0 = (blk & 15) * 64;

    const float* xg[2] = { x0 + b * 65536 + hw0, x1 + b * 65536 + hw0 };
    float* outg = out + b * 262144 + hw0;

    // lane-specific f32 W offset: fragment (widx,kb,i) for this lane is
    // W[widx][i*16+pl][kb*32 + q*8 .. +7]  (A-operand rows = out-channels)
    const int lo = pl * 64 + q * 8;
    #define WB(w) ((((w) < 2) ? (Wpre + (w) * 4096) : (Wedge + ((w) - 2) * 4096)) + lo)

    f16x8 wA[2][2][4];    // [parity][kb][m-tile], double-buffered one conv ahead
    #pragma unroll
    for (int kb = 0; kb < 2; ++kb)
        #pragma unroll
        for (int i = 0; i < 4; ++i)
            wA[0][kb][i] = cvt8(WB(0) + i * 1024 + kb * 32);

    // ---- cooperative input staging -> f16 [p][c] buffers 2 (x0), 3 (x1) ----
    {
        const int p = t & 63, h = t >> 6;       // h: channel half (32 ch)
        #pragma unroll
        for (int inp = 0; inp < 2; ++inp) {
            const float* src = xg[inp] + (h * 32) * 1024 + p;
            unsigned int u[16];
            #pragma unroll
            for (int i = 0; i < 16; ++i)
                u[i] = pkrtz(src[(2 * i) * 1024], src[(2 * i + 1) * 1024]);
            uint4* dst = (uint4*)(lds + (2 + inp) * SB + p * RSH + h * 32);
            dst[0] = make_uint4(u[0],  u[1],  u[2],  u[3]);
            dst[1] = make_uint4(u[4],  u[5],  u[6],  u[7]);
            dst[2] = make_uint4(u[8],  u[9],  u[10], u[11]);
            dst[3] = make_uint4(u[12], u[13], u[14], u[15]);
        }
    }
    __syncthreads();   // the ONLY barrier

    f32x4 accA[2][4] = {};   // [j-tile][m-tile]
    f32x4 accB[2][4] = {};

    const int widx_tab[16] = {0,1, 2,3, 4,5,6, 7,11, 8,12, 9,13, 14, 10, 15};
    const int src_tab [16] = {2,3, 0,1, 0,1,2, 0,0,  1,1,  2,2,  3,  3,  0};
    const int asel_tab[16] = {0,0, 0,0, 0,0,0, 0,1,  0,1,  0,1,  1,  0,  1};
    const int out_tab [16] = {-1,-1, -1,0, -1,-1,1, -1,-1, -1,-1, -1,-1, -1, 2, 3};
    const int dst_tab [16] = { 0, 1, -1,2, -1,-1,3, -1,-1, -1,-1, -1,-1, -1, 0,-1};

    #pragma unroll
    for (int k = 0; k < 16; ++k) {
        const int cur = k & 1, nxt = cur ^ 1;

        // prefetch W(k+1) fragments (f32 from L2, convert inline;
        // latency hidden by 16 MFMAs)
        if (k < 15) {
            const float* wn = WB(widx_tab[k + 1]);
            #pragma unroll
            for (int kb = 0; kb < 2; ++kb)
                #pragma unroll
                for (int i = 0; i < 4; ++i)
                    wA[nxt][kb][i] = cvt8(wn + i * 1024 + kb * 32);
        }

        // B fragments from this wave's own 32 state rows
        const f16* S = lds + src_tab[k] * SB;
        f16x8 bf[2][2];
        #pragma unroll
        for (int jj = 0; jj < 2; ++jj)
            #pragma unroll
            for (int kb = 0; kb < 2; ++kb)
                bf[jj][kb] = *(const f16x8*)(S + (wv * 32 + jj * 16 + pl) * RSH
                                               + kb * 32 + q * 8);

        auto step = [&](f32x4 (&acc)[2][4]) {
            #pragma unroll
            for (int jj = 0; jj < 2; ++jj)
                #pragma unroll
                for (int kb = 0; kb < 2; ++kb)
                    #pragma unroll
                    for (int i = 0; i < 4; ++i)
                        acc[jj][i] = __builtin_amdgcn_mfma_f32_16x16x32_f16(
                                         wA[cur][kb][i], bf[jj][kb], acc[jj][i], 0, 0, 0);
        };
        auto retire = [&](f32x4 (&acc)[2][4]) {
            if (out_tab[k] >= 0) {   // raw node state -> global
                #pragma unroll
                for (int jj = 0; jj < 2; ++jj) {
                    const int p = wv * 32 + jj * 16 + pl;
                    #pragma unroll
                    for (int i = 0; i < 4; ++i) {
                        const int c = i * 16 + q * 4;
                        #pragma unroll
                        for (int r = 0; r < 4; ++r)
                            outg[(out_tab[k] * 64 + c + r) * 1024 + p] = acc[jj][i][r];
                    }
                }
            }
            if (dst_tab[k] >= 0) {   // relu'd state -> own LDS rows
                f16* D = lds + dst_tab[k] * SB;
                #pragma unroll
                for (int jj = 0; jj < 2; ++jj) {
                    f16* Dp = D + (wv * 32 + jj * 16 + pl) * RSH;
                    #pragma unroll
                    for (int i = 0; i < 4; ++i) {
                        unsigned int u0 = pkrtz(fmaxf(acc[jj][i][0], 0.f),
                                                fmaxf(acc[jj][i][1], 0.f));
                        unsigned int u1 = pkrtz(fmaxf(acc[jj][i][2], 0.f),
                                                fmaxf(acc[jj][i][3], 0.f));
                        *(uint2*)(Dp + i * 16 + q * 4) = make_uint2(u0, u1);
                    }
                }
            }
            if (out_tab[k] >= 0 || dst_tab[k] >= 0) {
                #pragma unroll
                for (int jj = 0; jj < 2; ++jj)
                    #pragma unroll
                    for (int i = 0; i < 4; ++i)
                        acc[jj][i] = (f32x4){0.f, 0.f, 0.f, 0.f};
            }
        };

        if (asel_tab[k] == 0) { step(accA); retire(accA); }
        else                  { step(accB); retire(accB); }
    }
    #undef WB
}

extern "C" void kernel_launch(void* const* d_in, const int* in_sizes, int n_in,
                              void* d_out, int out_size, void* d_ws, size_t ws_size,
                              hipStream_t stream) {
    const float* x0    = (const float*)d_in[0];
    const float* x1    = (const float*)d_in[1];
    const float* Wpre  = (const float*)d_in[2];
    const float* Wedge = (const float*)d_in[3];
    float* outp        = (float*)d_out;
    (void)d_ws; (void)ws_size;

    dag_kernel<<<dim3(1024), dim3(128), 0, stream>>>(x0, x1, Wpre, Wedge, outp);
}

// Round 2
// 107.236 us; speedup vs baseline: 1.3530x; 1.3530x over previous
//
#include <hip/hip_runtime.h>

// DAG of 1x1 convs, fully fused, f16 MFMA, zero per-conv barriers.
// R8: revert R7's inline W-convert (uncoalesced, -40us). Back to 2-kernel
// structure + two latency fixes:
//  (a) operand-swapped MFMA (D = X*W^T) for all chains with global retires:
//      lane then holds 4 consecutive PIXELS per channel -> float4 stores
//      (32 dwordx4/wave instead of 128 scattered dword).
//  (b) W prefetch 2 convs ahead (triple-buffered wA) to cover ~200cy L2
//      latency; VGPRs are free (occupancy is LDS-bound at 2 waves/SIMD).
// Schedule (conv index k -> weight widx / src buf / acc / retire):
//  k  : 0  1  2  3  4  5  6  7  8  9 10 11 12 13 14 15
//  w  : 0  1  2  3  4  5  6  7 11  8 12  9 13 14 10 15   (0,1=pre; 2+e=edge e)
//  src: 2  3  0  1  0  1  2  0  0  1  1  2  2  3  3  0
//  acc: A  A  A  A  A  A  A  A  B  A  B  A  B  B  A  B
//  ret: s0 s1 -  n2 -  -  n3 -  -  -  -  -  -  -  n4 n5
// buffers: s0->0, s1->1, s2->2 (was xin0), s3->3 (was xin1), s4->0 (s0 dead)
// k0,k1 keep W*X order (vectorized LDS retire); k2..15 swapped (X*W^T).

typedef _Float16 f16;
typedef _Float16 f16x8 __attribute__((ext_vector_type(8)));
typedef float    f32x4 __attribute__((ext_vector_type(4)));

#define RSH 72            // f16 per state row (144B: 16B-aligned, 2-way banks)
#define SB  (64 * RSH)    // 4608 f16 = 9216 B per state buffer

__device__ __forceinline__ unsigned int pkrtz(float a, float b) {
    __fp16 h2 __attribute__((ext_vector_type(2))) = __builtin_amdgcn_cvt_pkrtz(a, b);
    return __builtin_bit_cast(unsigned int, h2);
}

// ---- kernel 1: W f32 [16][64][64] -> f16 fragment layout in ws ----
// flat u = ((k*2+kb)*4+q)*64 + row; ws[u*8 .. +7] = W[k][row][kb*32+q*8 .. +7]
__global__ __launch_bounds__(256) void wconv_kernel(
    const float* __restrict__ Wpre, const float* __restrict__ Wedge,
    f16* __restrict__ ws)
{
    const int u   = blockIdx.x * 256 + threadIdx.x;  // 0..8191
    const int k   = u >> 9;
    const int rem = u & 511;
    const int g   = rem >> 6;        // kb*4+q
    const int row = rem & 63;
    const float* src = ((k < 2) ? (Wpre + k * 4096) : (Wedge + (k - 2) * 4096))
                       + row * 64 + (g >> 2) * 32 + (g & 3) * 8;
    float4 v0 = ((const float4*)src)[0];
    float4 v1 = ((const float4*)src)[1];
    ((uint4*)ws)[u] = make_uint4(pkrtz(v0.x, v0.y), pkrtz(v0.z, v0.w),
                                 pkrtz(v1.x, v1.y), pkrtz(v1.z, v1.w));
}

// ---- kernel 2: the fused DAG ----
__global__ __launch_bounds__(128, 2) void dag_kernel(
    const float* __restrict__ x0, const float* __restrict__ x1,
    const f16* __restrict__ wf, float* __restrict__ out)
{
    __shared__ __align__(16) f16 lds[4 * SB];   // 36864 B -> 4 blocks/CU

    const int t    = threadIdx.x;   // 128 threads = 2 waves
    const int lane = t & 63;
    const int wv   = t >> 6;        // wave owns pixels wv*32 .. wv*32+31
    const int pl   = lane & 15;
    const int q    = lane >> 4;

    const int blk = blockIdx.x;     // 1024 = 64 batches x 16 px-tiles (4/CU, no tail)
    const int b   = blk >> 4;
    const int hw0 = (blk & 15) * 64;

    const float* xg[2] = { x0 + b * 65536 + hw0, x1 + b * 65536 + hw0 };
    float* outg = out + b * 262144 + hw0;

    const int widx_tab[16] = {0,1, 2,3, 4,5,6, 7,11, 8,12, 9,13, 14, 10, 15};
    const int src_tab [16] = {2,3, 0,1, 0,1,2, 0,0,  1,1,  2,2,  3,  3,  0};
    const int asel_tab[16] = {0,0, 0,0, 0,0,0, 0,1,  0,1,  0,1,  1,  0,  1};
    const int out_tab [16] = {-1,-1, -1,0, -1,-1,1, -1,-1, -1,-1, -1,-1, -1, 2, 3};
    const int dst_tab [16] = { 0, 1, -1,2, -1,-1,3, -1,-1, -1,-1, -1,-1, -1, 0,-1};

    // lane-specific W fragment base; frag(widx,kb,i) at + (widx*2+kb)*2048 + i*128
    const f16* wl = wf + q * 512 + pl * 8;

    f16x8 wA[3][2][4];    // [slot][kb][m-tile], prefetched TWO convs ahead
    #pragma unroll
    for (int s = 0; s < 2; ++s)
        #pragma unroll
        for (int kb = 0; kb < 2; ++kb)
            #pragma unroll
            for (int i = 0; i < 4; ++i)
                wA[s][kb][i] = *(const f16x8*)(wl + widx_tab[s] * 4096
                                               + kb * 2048 + i * 128);

    // ---- cooperative input staging -> f16 [p][c] buffers 2 (x0), 3 (x1) ----
    {
        const int p = t & 63, h = t >> 6;       // h: channel half (32 ch)
        #pragma unroll
        for (int inp = 0; inp < 2; ++inp) {
            const float* src = xg[inp] + (h * 32) * 1024 + p;
            unsigned int u[16];
            #pragma unroll
            for (int i = 0; i < 16; ++i)
                u[i] = pkrtz(src[(2 * i) * 1024], src[(2 * i + 1) * 1024]);
            uint4* dst = (uint4*)(lds + (2 + inp) * SB + p * RSH + h * 32);
            dst[0] = make_uint4(u[0],  u[1],  u[2],  u[3]);
            dst[1] = make_uint4(u[4],  u[5],  u[6],  u[7]);
            dst[2] = make_uint4(u[8],  u[9],  u[10], u[11]);
            dst[3] = make_uint4(u[12], u[13], u[14], u[15]);
        }
    }
    __syncthreads();   // the ONLY barrier

    f32x4 accA[2][4] = {};   // [j-tile][tile]
    f32x4 accB[2][4] = {};

    #pragma unroll
    for (int k = 0; k < 16; ++k) {
        const int cur = k % 3;

        // prefetch W(k+2) fragments (L2-resident f16, coalesced 1KB/instr;
        // ~2 convs of MFMA latency cover)
        if (k < 14) {
            const f16* wn = wl + widx_tab[k + 2] * 4096;
            const int s = (k + 2) % 3;
            #pragma unroll
            for (int kb = 0; kb < 2; ++kb)
                #pragma unroll
                for (int i = 0; i < 4; ++i)
                    wA[s][kb][i] = *(const f16x8*)(wn + kb * 2048 + i * 128);
        }

        // B fragments from this wave's own 32 state rows ([p][c] layout)
        const f16* S = lds + src_tab[k] * SB;
        f16x8 bf[2][2];
        #pragma unroll
        for (int jj = 0; jj < 2; ++jj)
            #pragma unroll
            for (int kb = 0; kb < 2; ++kb)
                bf[jj][kb] = *(const f16x8*)(S + (wv * 32 + jj * 16 + pl) * RSH
                                               + kb * 32 + q * 8);

        const bool swp = (k >= 2);   // operand-swapped chains (X * W^T)

        auto step = [&](f32x4 (&acc)[2][4]) {
            #pragma unroll
            for (int jj = 0; jj < 2; ++jj)
                #pragma unroll
                for (int kb = 0; kb < 2; ++kb)
                    #pragma unroll
                    for (int i = 0; i < 4; ++i)
                        acc[jj][i] = swp
                            ? __builtin_amdgcn_mfma_f32_16x16x32_f16(
                                  bf[jj][kb], wA[cur][kb][i], acc[jj][i], 0, 0, 0)
                            : __builtin_amdgcn_mfma_f32_16x16x32_f16(
                                  wA[cur][kb][i], bf[jj][kb], acc[jj][i], 0, 0, 0);
        };
        auto retire = [&](f32x4 (&acc)[2][4]) {
            if (out_tab[k] >= 0) {   // swapped: lane holds 4 consecutive pixels
                #pragma unroll
                for (int jj = 0; jj < 2; ++jj) {
                    const int p0 = wv * 32 + jj * 16 + q * 4;
                    #pragma unroll
                    for (int i = 0; i < 4; ++i)
                        *(f32x4*)(outg + (out_tab[k] * 64 + i * 16 + pl) * 1024
                                       + p0) = acc[jj][i];
                }
            }
            if (dst_tab[k] >= 0) {   // relu'd state -> own LDS rows ([p][c])
                f16* D = lds + dst_tab[k] * SB;
                if (!swp) {          // k=0,1: lane holds 4 channels / pixel
                    #pragma unroll
                    for (int jj = 0; jj < 2; ++jj) {
                        f16* Dp = D + (wv * 32 + jj * 16 + pl) * RSH;
                        #pragma unroll
                        for (int i = 0; i < 4; ++i) {
                            unsigned int u0 = pkrtz(fmaxf(acc[jj][i][0], 0.f),
                                                    fmaxf(acc[jj][i][1], 0.f));
                            unsigned int u1 = pkrtz(fmaxf(acc[jj][i][2], 0.f),
                                                    fmaxf(acc[jj][i][3], 0.f));
                            *(uint2*)(Dp + i * 16 + q * 4) = make_uint2(u0, u1);
                        }
                    }
                } else {             // swapped: 4 pixels / channel, scalar b16
                    #pragma unroll
                    for (int jj = 0; jj < 2; ++jj) {
                        const int p0 = wv * 32 + jj * 16 + q * 4;
                        #pragma unroll
                        for (int i = 0; i < 4; ++i)
                            #pragma unroll
                            for (int r = 0; r < 4; ++r)
                                D[(p0 + r) * RSH + i * 16 + pl] =
                                    (f16)fmaxf(acc[jj][i][r], 0.f);
                    }
                }
            }
            if (out_tab[k] >= 0 || dst_tab[k] >= 0) {
                #pragma unroll
                for (int jj = 0; jj < 2; ++jj)
                    #pragma unroll
                    for (int i = 0; i < 4; ++i)
                        acc[jj][i] = (f32x4){0.f, 0.f, 0.f, 0.f};
            }
        };

        if (asel_tab[k] == 0) { step(accA); retire(accA); }
        else                  { step(accB); retire(accB); }
    }
}

extern "C" void kernel_launch(void* const* d_in, const int* in_sizes, int n_in,
                              void* d_out, int out_size, void* d_ws, size_t ws_size,
                              hipStream_t stream) {
    const float* x0    = (const float*)d_in[0];
    const float* x1    = (const float*)d_in[1];
    const float* Wpre  = (const float*)d_in[2];
    const float* Wedge = (const float*)d_in[3];
    float* outp        = (float*)d_out;
    f16*   wfrag       = (f16*)d_ws;          // 131072 B used

    wconv_kernel<<<dim3(32), dim3(256), 0, stream>>>(Wpre, Wedge, wfrag);
    dag_kernel<<<dim3(1024), dim3(128), 0, stream>>>(x0, x1, wfrag, outp);
}

// Round 3
// 103.614 us; speedup vs baseline: 1.4003x; 1.0350x over previous
//
#include <hip/hip_runtime.h>

// DAG of 1x1 convs, fully fused, f16 MFMA.
// R9: channel-split 4-wave blocks. Each wave owns a 16-out-channel slice x
// all 64 pixels of the block -> 4096 waves (16/CU, 4/SIMD, 2x occupancy)
// and W fragment traffic per conv halves (8KB/block vs 16KB). States are
// block-shared in LDS (36KB -> 4 blocks/CU); 7 barriers, covered by
// cross-block overlap. Retires spread at k=4,9,13,15.
// Schedule (conv k -> weight widx / src buf / acc / retire):
//  k  : 0    1    2  3   4   5  6   7  8   9   10 11 12 13   14  15
//  w  : 0    1    2  11  3   4  12  5  13  6   7  8  9  10   14  15
//  src: 2    3    0  0   1   0  1   1  2   2   0  1  2  3    3   0
//  acc: A    A    A  B   A   A  B   A  B   A   A  A  A  A    B   B
//  ret: s0   s1   -  -   n2  -  -   -  -   n3  -  -  -  n4   -   n5
// buffers: s0->0, s1->1, n2->2 (was xin0), n3->3 (was xin1), n4->0 (s0 dead)
// barriers: after staging; after retire-writes at k=0,1,4,9,13; pre-write
// barrier at k=13 (protects k<=12 reads of buf0/s0 before n4 overwrites it).
// k=0,1 non-swapped (D=W*X, vectorized LDS retire); k>=2 swapped (D=X*W^T,
// float4 global stores). Edge accumulation order per node == reference.

typedef _Float16 f16;
typedef _Float16 f16x8 __attribute__((ext_vector_type(8)));
typedef float    f32x4 __attribute__((ext_vector_type(4)));

#define RSH 72            // f16 per state row (144B: 16B-aligned, 2-way banks)
#define SB  (64 * RSH)    // 4608 f16 = 9216 B per state buffer (64 px)

__device__ __forceinline__ unsigned int pkrtz(float a, float b) {
    __fp16 h2 __attribute__((ext_vector_type(2))) = __builtin_amdgcn_cvt_pkrtz(a, b);
    return __builtin_bit_cast(unsigned int, h2);
}

// ---- kernel 1: W f32 [16][64][64] -> f16 fragment layout in ws ----
// flat u = ((k*2+kb)*4+q)*64 + row; ws[u*8 .. +7] = W[k][row][kb*32+q*8 .. +7]
__global__ __launch_bounds__(256) void wconv_kernel(
    const float* __restrict__ Wpre, const float* __restrict__ Wedge,
    f16* __restrict__ ws)
{
    const int u   = blockIdx.x * 256 + threadIdx.x;  // 0..8191
    const int k   = u >> 9;
    const int rem = u & 511;
    const int g   = rem >> 6;        // kb*4+q
    const int row = rem & 63;
    const float* src = ((k < 2) ? (Wpre + k * 4096) : (Wedge + (k - 2) * 4096))
                       + row * 64 + (g >> 2) * 32 + (g & 3) * 8;
    float4 v0 = ((const float4*)src)[0];
    float4 v1 = ((const float4*)src)[1];
    ((uint4*)ws)[u] = make_uint4(pkrtz(v0.x, v0.y), pkrtz(v0.z, v0.w),
                                 pkrtz(v1.x, v1.y), pkrtz(v1.z, v1.w));
}

// ---- kernel 2: the fused DAG ----
__global__ __launch_bounds__(256, 4) void dag_kernel(
    const float* __restrict__ x0, const float* __restrict__ x1,
    const f16* __restrict__ wf, float* __restrict__ out)
{
    __shared__ __align__(16) f16 lds[4 * SB];   // 36864 B -> 4 blocks/CU

    const int t    = threadIdx.x;   // 256 threads = 4 waves
    const int lane = t & 63;
    const int w    = t >> 6;        // wave id = 16-channel output slice
    const int pl   = lane & 15;
    const int q    = lane >> 4;

    const int blk = blockIdx.x;     // 1024 = 64 batches x 16 px-tiles (4/CU)
    const int b   = blk >> 4;
    const int hw0 = (blk & 15) * 64;

    const float* xg[2] = { x0 + b * 65536 + hw0, x1 + b * 65536 + hw0 };
    float* outg = out + b * 262144 + hw0;

    // lane W fragment base; frag(widx,kb) at + widx*4096 + kb*2048
    // (rows = out-ch w*16+pl, cols kb*32+q*8 .. +7)
    const f16* wl = wf + q * 512 + (w * 16 + pl) * 8;

    f16x8 wA[2][2];    // [parity][kb], double-buffered one conv ahead
    #pragma unroll
    for (int kb = 0; kb < 2; ++kb)
        wA[0][kb] = *(const f16x8*)(wl + kb * 2048);

    // ---- cooperative input staging -> f16 [p][c] buffers 2 (x0), 3 (x1) ----
    // wave w stages channel quarter w (16 ch) for all 64 px.
    {
        const int p = t & 63, h = t >> 6;
        #pragma unroll
        for (int inp = 0; inp < 2; ++inp) {
            const float* src = xg[inp] + (h * 16) * 1024 + p;
            unsigned int u[8];
            #pragma unroll
            for (int i = 0; i < 8; ++i)
                u[i] = pkrtz(src[(2 * i) * 1024], src[(2 * i + 1) * 1024]);
            uint4* dst = (uint4*)(lds + (2 + inp) * SB + p * RSH + h * 16);
            dst[0] = make_uint4(u[0], u[1], u[2], u[3]);
            dst[1] = make_uint4(u[4], u[5], u[6], u[7]);
        }
    }
    __syncthreads();

    f32x4 accA[4] = {};   // [j-tile] (4 x 16 px), 16-ch slice
    f32x4 accB[4] = {};

    const int widx_tab[16] = {0,1, 2,11, 3, 4,12, 5,13, 6, 7, 8, 9,10, 14,15};
    const int src_tab [16] = {2,3, 0, 0, 1, 0, 1, 1, 2, 2, 0, 1, 2, 3,  3, 0};
    const int asel_tab[16] = {0,0, 0, 1, 0, 0, 1, 0, 1, 0, 0, 0, 0, 0,  1, 1};
    const int out_tab [16] = {-1,-1,-1,-1, 0,-1,-1,-1,-1, 1,-1,-1,-1, 2,-1, 3};
    const int dst_tab [16] = { 0, 1,-1,-1, 2,-1,-1,-1,-1, 3,-1,-1,-1, 0,-1,-1};

    #pragma unroll
    for (int k = 0; k < 16; ++k) {
        const int cur = k & 1, nxt = cur ^ 1;

        // prefetch W(k+1) slice (L1/L2-resident f16; 2 x 16B per lane)
        if (k < 15) {
            const f16* wn = wl + widx_tab[k + 1] * 4096;
            #pragma unroll
            for (int kb = 0; kb < 2; ++kb)
                wA[nxt][kb] = *(const f16x8*)(wn + kb * 2048);
        }

        // B fragments: all 64 px of the block ([p][c] LDS layout)
        const f16* S = lds + src_tab[k] * SB;
        f16x8 bf[4][2];
        #pragma unroll
        for (int jj = 0; jj < 4; ++jj)
            #pragma unroll
            for (int kb = 0; kb < 2; ++kb)
                bf[jj][kb] = *(const f16x8*)(S + (jj * 16 + pl) * RSH
                                               + kb * 32 + q * 8);

        const bool swp = (k >= 2);   // operand-swapped chains (X * W^T)

        auto step = [&](f32x4 (&acc)[4]) {
            #pragma unroll
            for (int jj = 0; jj < 4; ++jj)
                #pragma unroll
                for (int kb = 0; kb < 2; ++kb)
                    acc[jj] = swp
                        ? __builtin_amdgcn_mfma_f32_16x16x32_f16(
                              bf[jj][kb], wA[cur][kb], acc[jj], 0, 0, 0)
                        : __builtin_amdgcn_mfma_f32_16x16x32_f16(
                              wA[cur][kb], bf[jj][kb], acc[jj], 0, 0, 0);
        };
        auto retire = [&](f32x4 (&acc)[4]) {
            if (k == 13) __syncthreads();   // pre-write: all buf0(s0) reads done
            if (out_tab[k] >= 0) {   // swapped: lane holds 4 consecutive pixels
                #pragma unroll
                for (int jj = 0; jj < 4; ++jj)
                    *(f32x4*)(outg + (out_tab[k] * 64 + w * 16 + pl) * 1024
                                   + jj * 16 + q * 4) = acc[jj];
            }
            if (dst_tab[k] >= 0) {   // relu'd state -> LDS ([p][c])
                f16* D = lds + dst_tab[k] * SB;
                if (!swp) {          // k=0,1: lane holds ch w*16+q*4+r, px jj*16+pl
                    #pragma unroll
                    for (int jj = 0; jj < 4; ++jj) {
                        unsigned int u0 = pkrtz(fmaxf(acc[jj][0], 0.f),
                                                fmaxf(acc[jj][1], 0.f));
                        unsigned int u1 = pkrtz(fmaxf(acc[jj][2], 0.f),
                                                fmaxf(acc[jj][3], 0.f));
                        *(uint2*)(D + (jj * 16 + pl) * RSH + w * 16 + q * 4) =
                            make_uint2(u0, u1);
                    }
                } else {             // swapped: px jj*16+q*4+r, ch w*16+pl
                    #pragma unroll
                    for (int jj = 0; jj < 4; ++jj)
                        #pragma unroll
                        for (int r = 0; r < 4; ++r)
                            D[(jj * 16 + q * 4 + r) * RSH + w * 16 + pl] =
                                (f16)fmaxf(acc[jj][r], 0.f);
                }
            }
            if (out_tab[k] >= 0 || dst_tab[k] >= 0) {
                #pragma unroll
                for (int jj = 0; jj < 4; ++jj)
                    acc[jj] = (f32x4){0.f, 0.f, 0.f, 0.f};
            }
            if (dst_tab[k] >= 0) __syncthreads();  // publish state to all waves
        };

        if (asel_tab[k] == 0) { step(accA); retire(accA); }
        else                  { step(accB); retire(accB); }
    }
}

extern "C" void kernel_launch(void* const* d_in, const int* in_sizes, int n_in,
                              void* d_out, int out_size, void* d_ws, size_t ws_size,
                              hipStream_t stream) {
    const float* x0    = (const float*)d_in[0];
    const float* x1    = (const float*)d_in[1];
    const float* Wpre  = (const float*)d_in[2];
    const float* Wedge = (const float*)d_in[3];
    float* outp        = (float*)d_out;
    f16*   wfrag       = (f16*)d_ws;          // 131072 B used

    wconv_kernel<<<dim3(32), dim3(256), 0, stream>>>(Wpre, Wedge, wfrag);
    dag_kernel<<<dim3(1024), dim3(256), 0, stream>>>(x0, x1, wfrag, outp);
}